// Round 1
// baseline (168.258 us; speedup 1.0000x reference)
//
#include <hip/hip_runtime.h>

// privacyLoss1: result = (0.5/N) * sum_{i in [0,N-2], j in [1,N-1]} sign_ij * ||x_i - x_j||^2
// sign_ij = +1 if label_i == label_j else -1.
//
// Factorization: sign = 2*[same] - 1  =>  Total = 2*A - B with
//   A = sum_c [ nC_c*SsqR_c + nR_c*SsqC_c - 2*<VR_c, VC_c> ]
//   B = (N-1)*(SsqR + SsqC) - 2*<VR, VC>
// where R = all rows except N-1, C = all rows except 0. All terms derive from
// full-set per-class stats (n_c, Ssq_c, V_c) plus corrections with x_0, x_{N-1}.
// => single O(N*D) streaming pass instead of O(N^2 D) Gram matrix.

#define NCLS 10
#define NVALS 44  // 10 VV + 10 V0 + 10 VN + VVt,d0N,s0,sN + 10 cnt

__global__ __launch_bounds__(256) void zero_ws_kernel(float* __restrict__ p, int n) {
    int i = blockIdx.x * 256 + threadIdx.x;
    if (i < n) p[i] = 0.0f;
}

// Each block: 64 rows x 256 dims. Per-thread per-class register accumulation
// (static indexing via unrolled compare-select), then coalesced atomics.
__global__ __launch_bounds__(256) void accum_kernel(
        const float* __restrict__ x, const int* __restrict__ label,
        float* __restrict__ V, float* __restrict__ Ssq,
        int N, int D, int dimSlices, int rowsPerChunk) {
    const int t  = threadIdx.x;
    const int ds = blockIdx.x % dimSlices;
    const int rc = blockIdx.x / dimSlices;
    const int row0 = rc * rowsPerChunk;

    __shared__ int labs[64];
    if (t < rowsPerChunk && row0 + t < N) labs[t] = label[row0 + t];
    __syncthreads();

    const int d = ds * 256 + t;
    float vacc[NCLS], sacc[NCLS];
#pragma unroll
    for (int c = 0; c < NCLS; ++c) { vacc[c] = 0.0f; sacc[c] = 0.0f; }

    const float* p = x + (size_t)row0 * D + d;
    const int rows = (row0 + rowsPerChunk <= N) ? rowsPerChunk : (N - row0);
    for (int r = 0; r < rows; ++r) {
        float v = p[(size_t)r * D];
        int   l = labs[r];
        float s = v * v;
#pragma unroll
        for (int c = 0; c < NCLS; ++c) {
            bool m = (l == c);
            vacc[c] += m ? v : 0.0f;
            sacc[c] += m ? s : 0.0f;
        }
    }

    // V flush: per-class, consecutive threads hit consecutive addresses (coalesced atomics)
#pragma unroll
    for (int c = 0; c < NCLS; ++c) atomicAdd(&V[c * D + d], vacc[c]);

    // Ssq flush: wave-reduce first, one atomic per wave per class
    const int lane = t & 63;
#pragma unroll
    for (int c = 0; c < NCLS; ++c) {
        float v = sacc[c];
#pragma unroll
        for (int off = 32; off > 0; off >>= 1) v += __shfl_xor(v, off, 64);
        if (lane == 0) atomicAdd(&Ssq[c], v);
    }
}

// Single block: counts, small dot products, closed-form combine in double.
__global__ __launch_bounds__(256) void finalize_kernel(
        const float* __restrict__ x, const int* __restrict__ label,
        const float* __restrict__ V, const float* __restrict__ Ssq,
        float* __restrict__ result, int N, int D) {
    const int t    = threadIdx.x;
    const int lane = t & 63;
    const int wave = t >> 6;

    // per-class counts (exact in fp32: <= 4096)
    float cnt[NCLS];
#pragma unroll
    for (int c = 0; c < NCLS; ++c) cnt[c] = 0.0f;
    for (int i = t; i < N; i += 256) {
        int l = label[i];
#pragma unroll
        for (int c = 0; c < NCLS; ++c) cnt[c] += (l == c) ? 1.0f : 0.0f;
    }

    float VV[NCLS], V0[NCLS], VN[NCLS];
#pragma unroll
    for (int c = 0; c < NCLS; ++c) { VV[c] = 0.0f; V0[c] = 0.0f; VN[c] = 0.0f; }
    float VVt = 0.0f, d0N = 0.0f, s0 = 0.0f, sN = 0.0f;

    const float* x0 = x;
    const float* xN = x + (size_t)(N - 1) * D;
    for (int d = t; d < D; d += 256) {
        float a0 = x0[d], aN = xN[d];
        float vt = 0.0f;
#pragma unroll
        for (int c = 0; c < NCLS; ++c) {
            float v = V[c * D + d];
            VV[c] += v * v;
            V0[c] += v * a0;
            VN[c] += v * aN;
            vt    += v;
        }
        VVt += vt * vt;
        d0N += a0 * aN;
        s0  += a0 * a0;
        sN  += aN * aN;
    }

    float vals[NVALS];
#pragma unroll
    for (int c = 0; c < NCLS; ++c) {
        vals[c]      = VV[c];
        vals[10 + c] = V0[c];
        vals[20 + c] = VN[c];
        vals[34 + c] = cnt[c];
    }
    vals[30] = VVt; vals[31] = d0N; vals[32] = s0; vals[33] = sN;

    __shared__ float red[4][NVALS];
#pragma unroll
    for (int k = 0; k < NVALS; ++k) {
        float v = vals[k];
#pragma unroll
        for (int off = 32; off > 0; off >>= 1) v += __shfl_xor(v, off, 64);
        if (lane == 0) red[wave][k] = v;
    }
    __syncthreads();

    if (t == 0) {
        double v[NVALS];
        for (int k = 0; k < NVALS; ++k)
            v[k] = (double)red[0][k] + (double)red[1][k] + (double)red[2][k] + (double)red[3][k];

        const int l0 = label[0];
        const int lN = label[N - 1];
        const double sq0 = v[32], sqN = v[33], dON = v[31], VVtd = v[30];

        double A = 0.0, SsqTot = 0.0, Vt0 = 0.0, VtN = 0.0;
        for (int c = 0; c < NCLS; ++c) {
            double nc   = v[34 + c];
            double Ssqc = (double)Ssq[c];
            SsqTot += Ssqc;
            Vt0    += v[10 + c];
            VtN    += v[20 + c];
            double ac = (lN == c) ? 1.0 : 0.0;  // excluded from rows R
            double bc = (l0 == c) ? 1.0 : 0.0;  // excluded from cols C
            double nR = nc - ac, nC = nc - bc;
            double SsqR  = Ssqc - ac * sqN;
            double SsqC  = Ssqc - bc * sq0;
            double dotRC = v[c] - bc * v[10 + c] - ac * v[20 + c] + ac * bc * dON;
            A += nC * SsqR + nR * SsqC - 2.0 * dotRC;
        }
        double Bv = (double)(N - 1) * ((SsqTot - sqN) + (SsqTot - sq0))
                  - 2.0 * (VVtd - Vt0 - VtN + dON);
        double total = 2.0 * A - Bv;
        result[0] = (float)((0.5 / (double)N) * total);
    }
}

extern "C" void kernel_launch(void* const* d_in, const int* in_sizes, int n_in,
                              void* d_out, int out_size, void* d_ws, size_t ws_size,
                              hipStream_t stream) {
    const float* x     = (const float*)d_in[0];
    const int*   label = (const int*)d_in[1];
    const int N = in_sizes[1];
    const int D = in_sizes[0] / N;   // 1024

    float* V   = (float*)d_ws;           // [NCLS][D]
    float* Ssq = V + NCLS * D;           // [NCLS]
    float* result = (float*)d_out;

    const int nz = NCLS * D + NCLS;
    zero_ws_kernel<<<(nz + 255) / 256, 256, 0, stream>>>(V, nz);

    const int rowsPerChunk = 64;
    const int dimSlices = (D + 255) / 256;                       // 4 for D=1024
    const int rowChunks = (N + rowsPerChunk - 1) / rowsPerChunk; // 64 for N=4096
    accum_kernel<<<rowChunks * dimSlices, 256, 0, stream>>>(
        x, label, V, Ssq, N, D, dimSlices, rowsPerChunk);

    finalize_kernel<<<1, 256, 0, stream>>>(x, label, V, Ssq, result, N, D);
}

// Round 2
// 42.118 us; speedup vs baseline: 3.9949x; 3.9949x over previous
//
#include <hip/hip_runtime.h>

// privacyLoss1: result = (0.5/N) * sum_{i in [0,N-2], j in [1,N-1]} sign_ij * ||x_i - x_j||^2
// sign_ij = +1 if label_i == label_j else -1.
//
// Factorization: sign = 2*[same] - 1  =>  Total = 2*A - B with
//   A = sum_c [ nC_c*SsqR_c + nR_c*SsqC_c - 2*<VR_c, VC_c> ]
//   B = (N-1)*(SsqR + SsqC) - 2*<VR, VC>
// R = rows except N-1, C = rows except 0. All terms derive from full-set
// per-class stats (n_c, Ssq_c, V_c) + O(D) corrections with x_0, x_{N-1}.
// => O(N*D) streaming instead of O(N^2 D).
//
// v2: atomic-free 3-phase tree. Phase1: (row-group x dim-slice) blocks with
// float4 loads + register per-class accum -> disjoint partial slabs in ws.
// Phase2: reduce partials -> V[10][D]. Phase3: closed-form combine (fp64).

#define NCLS 10
#define NVALS 54  // 10 VV + 10 V0 + 10 VN + VVt,d0N,s0,sN + 10 cnt + 10 Ssq

// ---------------- phase 1: per-(group,slice) partial stats ----------------
__global__ __launch_bounds__(256) void partial_kernel(
        const float* __restrict__ x, const int* __restrict__ label,
        float* __restrict__ Vpart, float* __restrict__ Spart,
        int N, int D, int S, int rowsPerBlock) {
    const int t = threadIdx.x;
    const int s = blockIdx.x % S;           // 64-float dim slice
    const int g = blockIdx.x / S;           // row group
    const int row0 = g * rowsPerBlock;
    const int rows = min(rowsPerBlock, N - row0);

    __shared__ int labs[256];
    for (int r = t; r < rows; r += 256) labs[r] = label[row0 + r];
    __syncthreads();

    const int sub = t >> 4;   // 0..15 row offset within group
    const int l16 = t & 15;   // float4 slot within 64-float slice

    float4 vacc[NCLS];
    float  sacc[NCLS];
#pragma unroll
    for (int c = 0; c < NCLS; ++c) {
        vacc[c] = make_float4(0.f, 0.f, 0.f, 0.f);
        sacc[c] = 0.f;
    }

    const float* bp = x + (size_t)row0 * D + s * 64 + l16 * 4;
#pragma unroll 4
    for (int r = sub; r < rows; r += 16) {
        float4 v = *(const float4*)(bp + (size_t)r * D);
        int l = labs[r];
        float sq = v.x * v.x + v.y * v.y + v.z * v.z + v.w * v.w;
#pragma unroll
        for (int c = 0; c < NCLS; ++c) {
            float m = (l == c) ? 1.0f : 0.0f;
            vacc[c].x = fmaf(m, v.x, vacc[c].x);
            vacc[c].y = fmaf(m, v.y, vacc[c].y);
            vacc[c].z = fmaf(m, v.z, vacc[c].z);
            vacc[c].w = fmaf(m, v.w, vacc[c].w);
            sacc[c]   = fmaf(m, sq, sacc[c]);
        }
    }

    // reduce over in-wave sub bits (lane bits 4,5); sacc over whole wave
#pragma unroll
    for (int c = 0; c < NCLS; ++c) {
        vacc[c].x += __shfl_xor(vacc[c].x, 16, 64);
        vacc[c].y += __shfl_xor(vacc[c].y, 16, 64);
        vacc[c].z += __shfl_xor(vacc[c].z, 16, 64);
        vacc[c].w += __shfl_xor(vacc[c].w, 16, 64);
        vacc[c].x += __shfl_xor(vacc[c].x, 32, 64);
        vacc[c].y += __shfl_xor(vacc[c].y, 32, 64);
        vacc[c].z += __shfl_xor(vacc[c].z, 32, 64);
        vacc[c].w += __shfl_xor(vacc[c].w, 32, 64);
#pragma unroll
        for (int off = 32; off > 0; off >>= 1)
            sacc[c] += __shfl_xor(sacc[c], off, 64);
    }

    const int w = t >> 6;
    __shared__ float lsv[4][NCLS][64];
    __shared__ float lss[4][NCLS];
    if ((t & 63) < 16) {
#pragma unroll
        for (int c = 0; c < NCLS; ++c)
            *(float4*)&lsv[w][c][l16 * 4] = vacc[c];
    }
    if ((t & 63) == 0) {
#pragma unroll
        for (int c = 0; c < NCLS; ++c) lss[w][c] = sacc[c];
    }
    __syncthreads();

    for (int e = t; e < NCLS * 64; e += 256) {
        int c = e >> 6, dd = e & 63;
        float vs = lsv[0][c][dd] + lsv[1][c][dd] + lsv[2][c][dd] + lsv[3][c][dd];
        Vpart[((size_t)g * NCLS + c) * D + s * 64 + dd] = vs;
    }
    if (t < NCLS)
        Spart[(size_t)blockIdx.x * NCLS + t] =
            lss[0][t] + lss[1][t] + lss[2][t] + lss[3][t];
}

// ---------------- phase 2: sum group partials -> V[10][D] ----------------
__global__ __launch_bounds__(256) void reduceV_kernel(
        const float* __restrict__ Vpart, float* __restrict__ V, int D, int G) {
    const int t = threadIdx.x;
    const int d0 = blockIdx.x * 16;
    for (int e = t; e < NCLS * 16; e += 256) {
        int c = e >> 4, dd = e & 15;
        size_t off = (size_t)c * D + d0 + dd;
        float acc = 0.f;
#pragma unroll 4
        for (int g = 0; g < G; ++g)
            acc += Vpart[(size_t)g * NCLS * D + off];
        V[off] = acc;
    }
}

// ------------- fallback (tiny ws): atomic single-pass (v1 path) -------------
__global__ __launch_bounds__(256) void zero_ws_kernel(float* __restrict__ p, int n) {
    int i = blockIdx.x * 256 + threadIdx.x;
    if (i < n) p[i] = 0.0f;
}

__global__ __launch_bounds__(256) void accum_kernel(
        const float* __restrict__ x, const int* __restrict__ label,
        float* __restrict__ V, float* __restrict__ Ssq,
        int N, int D, int dimSlices, int rowsPerChunk) {
    const int t  = threadIdx.x;
    const int ds = blockIdx.x % dimSlices;
    const int rc = blockIdx.x / dimSlices;
    const int row0 = rc * rowsPerChunk;

    __shared__ int labs[64];
    if (t < rowsPerChunk && row0 + t < N) labs[t] = label[row0 + t];
    __syncthreads();

    const int d = ds * 256 + t;
    float vacc[NCLS], sacc[NCLS];
#pragma unroll
    for (int c = 0; c < NCLS; ++c) { vacc[c] = 0.0f; sacc[c] = 0.0f; }

    const float* p = x + (size_t)row0 * D + d;
    const int rows = (row0 + rowsPerChunk <= N) ? rowsPerChunk : (N - row0);
    for (int r = 0; r < rows; ++r) {
        float v = p[(size_t)r * D];
        int   l = labs[r];
        float sq = v * v;
#pragma unroll
        for (int c = 0; c < NCLS; ++c) {
            float m = (l == c) ? 1.0f : 0.0f;
            vacc[c] = fmaf(m, v, vacc[c]);
            sacc[c] = fmaf(m, sq, sacc[c]);
        }
    }
#pragma unroll
    for (int c = 0; c < NCLS; ++c) atomicAdd(&V[c * D + d], vacc[c]);
    const int lane = t & 63;
#pragma unroll
    for (int c = 0; c < NCLS; ++c) {
        float v = sacc[c];
#pragma unroll
        for (int off = 32; off > 0; off >>= 1) v += __shfl_xor(v, off, 64);
        if (lane == 0) atomicAdd(&Ssq[c], v);
    }
}

// ---------------- phase 3: closed-form combine in double ----------------
__global__ __launch_bounds__(256) void finalize_kernel(
        const float* __restrict__ x, const int* __restrict__ label,
        const float* __restrict__ V, const float* __restrict__ Spart, int nSpart,
        float* __restrict__ result, int N, int D) {
    const int t    = threadIdx.x;
    const int lane = t & 63;
    const int wave = t >> 6;

    float cnt[NCLS];
#pragma unroll
    for (int c = 0; c < NCLS; ++c) cnt[c] = 0.0f;
    for (int i = t; i < N; i += 256) {
        int l = label[i];
#pragma unroll
        for (int c = 0; c < NCLS; ++c) cnt[c] += (l == c) ? 1.0f : 0.0f;
    }

    float VV[NCLS], V0[NCLS], VN[NCLS];
#pragma unroll
    for (int c = 0; c < NCLS; ++c) { VV[c] = 0.0f; V0[c] = 0.0f; VN[c] = 0.0f; }
    float VVt = 0.0f, d0N = 0.0f, s0 = 0.0f, sN = 0.0f;

    const float* x0 = x;
    const float* xN = x + (size_t)(N - 1) * D;
    for (int d = t; d < D; d += 256) {
        float a0 = x0[d], aN = xN[d];
        float vt = 0.0f;
#pragma unroll
        for (int c = 0; c < NCLS; ++c) {
            float v = V[c * D + d];
            VV[c] += v * v;
            V0[c] += v * a0;
            VN[c] += v * aN;
            vt    += v;
        }
        VVt += vt * vt;
        d0N += a0 * aN;
        s0  += a0 * a0;
        sN  += aN * aN;
    }

    float ssqp[NCLS];
#pragma unroll
    for (int c = 0; c < NCLS; ++c) ssqp[c] = 0.0f;
    for (int b = t; b < nSpart; b += 256) {
#pragma unroll
        for (int c = 0; c < NCLS; ++c) ssqp[c] += Spart[(size_t)b * NCLS + c];
    }

    float vals[NVALS];
#pragma unroll
    for (int c = 0; c < NCLS; ++c) {
        vals[c]      = VV[c];
        vals[10 + c] = V0[c];
        vals[20 + c] = VN[c];
        vals[34 + c] = cnt[c];
        vals[44 + c] = ssqp[c];
    }
    vals[30] = VVt; vals[31] = d0N; vals[32] = s0; vals[33] = sN;

    __shared__ float red[4][NVALS];
#pragma unroll
    for (int k = 0; k < NVALS; ++k) {
        float v = vals[k];
#pragma unroll
        for (int off = 32; off > 0; off >>= 1) v += __shfl_xor(v, off, 64);
        if (lane == 0) red[wave][k] = v;
    }
    __syncthreads();

    if (t == 0) {
        double v[NVALS];
        for (int k = 0; k < NVALS; ++k)
            v[k] = (double)red[0][k] + (double)red[1][k] + (double)red[2][k] + (double)red[3][k];

        const int l0 = label[0];
        const int lN = label[N - 1];
        const double sq0 = v[32], sqN = v[33], dON = v[31], VVtd = v[30];

        double A = 0.0, SsqTot = 0.0, Vt0 = 0.0, VtN = 0.0;
        for (int c = 0; c < NCLS; ++c) {
            double nc   = v[34 + c];
            double Ssqc = v[44 + c];
            SsqTot += Ssqc;
            Vt0    += v[10 + c];
            VtN    += v[20 + c];
            double ac = (lN == c) ? 1.0 : 0.0;  // excluded from rows R
            double bc = (l0 == c) ? 1.0 : 0.0;  // excluded from cols C
            double nR = nc - ac, nC = nc - bc;
            double SsqR  = Ssqc - ac * sqN;
            double SsqC  = Ssqc - bc * sq0;
            double dotRC = v[c] - bc * v[10 + c] - ac * v[20 + c] + ac * bc * dON;
            A += nC * SsqR + nR * SsqC - 2.0 * dotRC;
        }
        double Bv = (double)(N - 1) * ((SsqTot - sqN) + (SsqTot - sq0))
                  - 2.0 * (VVtd - Vt0 - VtN + dON);
        double total = 2.0 * A - Bv;
        result[0] = (float)((0.5 / (double)N) * total);
    }
}

extern "C" void kernel_launch(void* const* d_in, const int* in_sizes, int n_in,
                              void* d_out, int out_size, void* d_ws, size_t ws_size,
                              hipStream_t stream) {
    const float* x     = (const float*)d_in[0];
    const int*   label = (const int*)d_in[1];
    const int N = in_sizes[1];
    const int D = in_sizes[0] / N;   // 1024
    float* result = (float*)d_out;

    const int S = D / 64;            // 16 dim-slices of 64 floats

    // pick row-group size so partial slabs fit in ws
    size_t wsFloats = ws_size / sizeof(float);
    int rpb = 0, Ga = 0;
    const int cands[3] = {64, 128, 256};
    for (int i = 0; i < 3; ++i) {
        int G = (N + cands[i] - 1) / cands[i];
        size_t need = (size_t)G * NCLS * D + (size_t)G * S * NCLS + (size_t)NCLS * D;
        if (need <= wsFloats) { rpb = cands[i]; Ga = G; break; }
    }

    if (Ga > 0 && (D % 64) == 0 && (D % 16) == 0) {
        float* Vpart = (float*)d_ws;                         // [Ga][NCLS][D]
        float* Spart = Vpart + (size_t)Ga * NCLS * D;        // [Ga*S][NCLS]
        float* V     = Spart + (size_t)Ga * S * NCLS;        // [NCLS][D]
        partial_kernel<<<Ga * S, 256, 0, stream>>>(x, label, Vpart, Spart, N, D, S, rpb);
        reduceV_kernel<<<D / 16, 256, 0, stream>>>(Vpart, V, D, Ga);
        finalize_kernel<<<1, 256, 0, stream>>>(x, label, V, Spart, Ga * S, result, N, D);
    } else {
        // tiny-ws fallback: v1 atomic path (41 KB)
        float* V   = (float*)d_ws;
        float* Ssq = V + NCLS * D;
        const int nz = NCLS * D + NCLS;
        zero_ws_kernel<<<(nz + 255) / 256, 256, 0, stream>>>(V, nz);
        const int rowsPerChunk = 64;
        const int dimSlices = (D + 255) / 256;
        const int rowChunks = (N + rowsPerChunk - 1) / rowsPerChunk;
        accum_kernel<<<rowChunks * dimSlices, 256, 0, stream>>>(
            x, label, V, Ssq, N, D, dimSlices, rowsPerChunk);
        finalize_kernel<<<1, 256, 0, stream>>>(x, label, V, Ssq, 1, result, N, D);
    }
}